// Round 12
// baseline (159.952 us; speedup 1.0000x reference)
//
#include <hip/hip_runtime.h>
#include <hip/hip_bf16.h>

#define B_DIM 4096
#define M_DIM 4096
#define K_DIM 4096
#define NCODE 512

typedef __attribute__((ext_vector_type(4))) float f32x4;
typedef __attribute__((ext_vector_type(8))) short short8;

__device__ __forceinline__ unsigned short f2bf(float f) {
    union { float f; unsigned u; } c; c.f = f;
    unsigned u = c.u;
    return (unsigned short)((u + 0x7FFFu + ((u >> 16) & 1u)) >> 16);
}

// ---------------------------------------------------------------------------
// Fused prep: blocks [0,8192) dequantize codes -> bf16 W; [8192,16384) cvt A.
// ---------------------------------------------------------------------------
__global__ __launch_bounds__(256) void prep_kernel(const int* __restrict__ Q,
                                                   const float* __restrict__ cb,
                                                   short* __restrict__ Wout,
                                                   const float* __restrict__ in,
                                                   short* __restrict__ Ab) {
    const int b = blockIdx.x;
    if (b < 8192) {
        const int t = b * 256 + threadIdx.x;
        const int code = Q[t] & 0xFFFF;
        const float4* g = (const float4*)(cb + (size_t)code * 8);
        const float4 v0 = g[0];
        const float4 v1 = g[1];
        short8 o;
        o[0] = f2bf(v0.x); o[1] = f2bf(v0.y); o[2] = f2bf(v0.z); o[3] = f2bf(v0.w);
        o[4] = f2bf(v1.x); o[5] = f2bf(v1.y); o[6] = f2bf(v1.z); o[7] = f2bf(v1.w);
        *(short8*)(Wout + (size_t)t * 8) = o;
    } else {
        const int t = (b - 8192) * 256 + threadIdx.x;
        const float4* p = (const float4*)(in + (size_t)t * 8);
        const float4 v0 = p[0];
        const float4 v1 = p[1];
        short8 o;
        o[0] = f2bf(v0.x); o[1] = f2bf(v0.y); o[2] = f2bf(v0.z); o[3] = f2bf(v0.w);
        o[4] = f2bf(v1.x); o[5] = f2bf(v1.y); o[6] = f2bf(v1.z); o[7] = f2bf(v1.w);
        *(short8*)(Ab + (size_t)t * 8) = o;
    }
}

// ---------------------------------------------------------------------------
// GEMM: C[B,M] = A[B,K] * W[M,K]^T — 256x128 tile, BK=32, 4 waves (2x2, wave
// tile 128x64 = r8's), 16x16x32 MFMA, 3-deep LDS ring (72 KB -> 2 blocks/CU:
// two INDEPENDENT barrier domains per CU decorrelate stalls), reg-decoupled
// 2-phase pipeline with counted vmcnt(6):
//   ph0: read a1 = cur-tile m4-7 (4 ds) ; issue 6 GLD(t+2) -> buf((t+2)%3) ;
//        MFMA m0-3 (aC,bC from prev iter)
//   ph1: MFMA m4-7 (a1,bC) ; vmcnt(6) ; barrier ;
//        read aC (m0-3) + bC (n0-3) from buf((t+1)%3)   [consumed next iter]
// Hazard audit:
//  - visibility: at ph1(t), outstanding = GLD(t+1)x6 (issued ph0(t-1)) +
//    GLD(t+2)x6 (issued ph0(t)) = 12; vmcnt(6) drains tile t+1 (issued a full
//    iter ~2000 cy earlier — covers HBM latency); barrier publishes; the
//    aC/bC reads of buf((t+1)%3) follow the barrier.
//  - overwrite: GLD(t+2)->buf((t+2)%3) at ph0(t); previous tenant tile t-1's
//    reads: aC/bC(t-1) (issued ph1(t-2), consumed by ph0(t-1) MFMA) and
//    a1(t-1) (issued ph0(t-1), consumed by ph1(t-1) MFMA) — all compiler-
//    drained BEFORE barrier(t-1) < GLD issue. SAFE.
//  - prologue: stage tiles 0,1 (12 GLD); vmcnt(6) drains tile 0; barrier.
//  - tail: t+2 clamps to NT-1 (dup-writes a dead buffer, same fence); last
//    iter's trailing reads hit an in-bounds dead buffer (values unused).
// LDS swizzle (BK=32 rows = 4 x 16B units): stored unit = u ^ (row&3);
// read slot = 4*(row&1) + su -> uniform 8 lanes/slot (balanced, conflict-
// free); GLOBAL source inverse-swizzled; staging dest = 16B x tid (linear,
// wave-uniform-base + lane x 16 as global_load_lds requires).
// ---------------------------------------------------------------------------
#define BM 256
#define BN 128
#define BK 32
#define NT (K_DIM / BK)   // 128
#define BUFS 12288        // shorts per ring slot (A 8192 | B 4096) = 24 KB

#define GLD(src, dst) \
    __builtin_amdgcn_global_load_lds( \
        (const __attribute__((address_space(1))) void*)(src), \
        (__attribute__((address_space(3))) void*)(dst), 16, 0, 0)

#define MFMA(a, b, c) __builtin_amdgcn_mfma_f32_16x16x32_bf16(a, b, c, 0, 0, 0)

__global__ __launch_bounds__(256, 2) void gemm_bt_kernel(const short* __restrict__ A,
                                                         const short* __restrict__ Wd,
                                                         float* __restrict__ C) {
    __shared__ short lds[3 * BUFS];   // 72 KB -> 2 blocks/CU

    const int tid  = threadIdx.x;
    const int wave = tid >> 6;
    const int lane = tid & 63;

    // XCD-chunked swizzle: 512 blocks -> 8 XCDs, chunk = 4 by x 16 bx
    const int bid = blockIdx.x;
    const int xcd = bid & 7;
    const int s   = bid >> 3;                 // 0..63
    const int by  = (xcd >> 1) * 4 + (s >> 4);   // 0..15
    const int bx  = (xcd & 1) * 16 + (s & 15);   // 0..31

    const int rowBase = by * BM;
    const int colBase = bx * BN;

    const int wr = wave >> 1;                 // 0..1  (128-row half)
    const int wc = wave & 1;                  // 0..1  (64-col half)

    // ---- staging: thread covers rows (tid>>2)+c*64, stored unit tid&3 ----
    const int rA0 = tid >> 2;                 // 0..63
    const int uu  = (tid & 3) ^ (rA0 & 3);    // inverse-swizzled logical unit
    const int stOff = rA0 * 32 + (tid & 3) * 8;   // shorts; == tid*8 (linear)
    const short* aSrcB = A  + (size_t)(rowBase + rA0) * K_DIM + uu * 8;
    const short* bSrcB = Wd + (size_t)(colBase + rA0) * K_DIM + uu * 8;

    // stage one tile tt into ring slot base (6 GLDs: A c=0..3, B c=0..1)
#define STAGE(tt, base) { \
        const size_t ko = (size_t)(tt) * BK; \
        GLD(aSrcB + ko,                 &lds[(base) + stOff]); \
        GLD(aSrcB + ko + 1 * 64 * K_DIM, &lds[(base) + 2048 + stOff]); \
        GLD(aSrcB + ko + 2 * 64 * K_DIM, &lds[(base) + 4096 + stOff]); \
        GLD(aSrcB + ko + 3 * 64 * K_DIM, &lds[(base) + 6144 + stOff]); \
        GLD(bSrcB + ko,                 &lds[(base) + 8192 + stOff]); \
        GLD(bSrcB + ko + 1 * 64 * K_DIM, &lds[(base) + 8192 + 2048 + stOff]); }

    // ---- fragment read offsets (shorts, within a ring slot) ----
    const int l15 = lane & 15;
    const int l4  = lane >> 4;                // 0..3 (16B unit)
    const int sx  = l15 & 3;
    const int aRd = (wr * 128 + l15) * 32 + (l4 ^ sx) * 8;          // + m*512
    const int bRd = 8192 + (wc * 64 + l15) * 32 + (l4 ^ sx) * 8;    // + n*512

    f32x4 acc[8][4] = {};
    short8 aC[4], bC[4];      // ph0 operands (loop-carried, read at ph1-end)

    // ---- prologue: stage tiles 0,1 ----
    STAGE(0, 0);
    STAGE(1, BUFS);
    asm volatile("s_waitcnt vmcnt(6)" ::: "memory");   // tile 0 landed
    __builtin_amdgcn_s_barrier();
#pragma unroll
    for (int m = 0; m < 4; ++m) aC[m] = *(const short8*)&lds[aRd + m * 512];
#pragma unroll
    for (int n = 0; n < 4; ++n) bC[n] = *(const short8*)&lds[bRd + n * 512];

    int bi = 0;                               // t % 3
    for (int t = 0; t < NT; ++t) {
        const int cur  = bi * BUFS;
        const int bn1i = (bi + 1 < 3) ? (bi + 1) : 0;   // (t+1)%3
        const int bn2i = (bn1i + 1 < 3) ? (bn1i + 1) : 0; // (t+2)%3
        const int bn1  = bn1i * BUFS;
        const int bn2  = bn2i * BUFS;
        const int t2c  = (t + 2 < NT) ? (t + 2) : (NT - 1);

        // ---- ph0: read a1 (m4-7) ; 6 GLD(t+2) ; MFMA m0-3 ----
        short8 a1[4];
#pragma unroll
        for (int m = 0; m < 4; ++m)
            a1[m] = *(const short8*)&lds[cur + aRd + (m + 4) * 512];
        STAGE(t2c, bn2);
        __builtin_amdgcn_s_setprio(1);
#pragma unroll
        for (int m = 0; m < 4; ++m)
#pragma unroll
            for (int n = 0; n < 4; ++n)
                acc[m][n] = MFMA(aC[m], bC[n], acc[m][n]);
        __builtin_amdgcn_s_setprio(0);

        // ---- ph1: MFMA m4-7 ; vmcnt(6)+barrier ; read next-tile frags ----
        __builtin_amdgcn_s_setprio(1);
#pragma unroll
        for (int m = 0; m < 4; ++m)
#pragma unroll
            for (int n = 0; n < 4; ++n)
                acc[m + 4][n] = MFMA(a1[m], bC[n], acc[m + 4][n]);
        __builtin_amdgcn_s_setprio(0);
        asm volatile("s_waitcnt vmcnt(6)" ::: "memory");   // tile t+1 landed
        __builtin_amdgcn_s_barrier();
#pragma unroll
        for (int m = 0; m < 4; ++m)
            aC[m] = *(const short8*)&lds[bn1 + aRd + m * 512];
#pragma unroll
        for (int n = 0; n < 4; ++n)
            bC[n] = *(const short8*)&lds[bn1 + bRd + n * 512];

        bi = bn1i;
    }

    // epilogue: C/D layout col = lane&15, row = (lane>>4)*4 + reg
    const int r0 = rowBase + wr * 128 + l4 * 4;
    const int c0 = colBase + wc * 64 + l15;
#pragma unroll
    for (int m = 0; m < 8; ++m)
#pragma unroll
        for (int n = 0; n < 4; ++n) {
            float* cp = C + (size_t)(r0 + m * 16) * M_DIM + (c0 + n * 16);
#pragma unroll
            for (int reg = 0; reg < 4; ++reg)
                cp[(size_t)reg * M_DIM] = acc[m][n][reg];
        }
}

// ---------------------------------------------------------------------------
extern "C" void kernel_launch(void* const* d_in, const int* in_sizes, int n_in,
                              void* d_out, int out_size, void* d_ws, size_t ws_size,
                              hipStream_t stream) {
    const float* inp  = (const float*)d_in[0];
    const int*   qidx = (const int*)d_in[1];
    const float* cb   = (const float*)d_in[2];
    float* out = (float*)d_out;

    short* Wb = (short*)d_ws;
    short* Ab = Wb + (size_t)M_DIM * K_DIM;

    prep_kernel<<<16384, 256, 0, stream>>>(qidx, cb, Wb, inp, Ab);

    gemm_bt_kernel<<<512, 256, 0, stream>>>(Ab, Wb, out);
}

// Round 13
// 159.787 us; speedup vs baseline: 1.0010x; 1.0010x over previous
//
#include <hip/hip_runtime.h>
#include <hip/hip_bf16.h>

#define B_DIM 4096
#define M_DIM 4096
#define K_DIM 4096
#define NCODE 512

typedef __attribute__((ext_vector_type(4))) float f32x4;
typedef __attribute__((ext_vector_type(8))) short short8;

__device__ __forceinline__ unsigned short f2bf(float f) {
    union { float f; unsigned u; } c; c.f = f;
    unsigned u = c.u;
    return (unsigned short)((u + 0x7FFFu + ((u >> 16) & 1u)) >> 16);
}

// ---------------------------------------------------------------------------
// Fused prep: blocks [0,8192) dequantize codes -> bf16 W; [8192,16384) cvt A.
// ---------------------------------------------------------------------------
__global__ __launch_bounds__(256) void prep_kernel(const int* __restrict__ Q,
                                                   const float* __restrict__ cb,
                                                   short* __restrict__ Wout,
                                                   const float* __restrict__ in,
                                                   short* __restrict__ Ab) {
    const int b = blockIdx.x;
    if (b < 8192) {
        const int t = b * 256 + threadIdx.x;
        const int code = Q[t] & 0xFFFF;
        const float4* g = (const float4*)(cb + (size_t)code * 8);
        const float4 v0 = g[0];
        const float4 v1 = g[1];
        short8 o;
        o[0] = f2bf(v0.x); o[1] = f2bf(v0.y); o[2] = f2bf(v0.z); o[3] = f2bf(v0.w);
        o[4] = f2bf(v1.x); o[5] = f2bf(v1.y); o[6] = f2bf(v1.z); o[7] = f2bf(v1.w);
        *(short8*)(Wout + (size_t)t * 8) = o;
    } else {
        const int t = (b - 8192) * 256 + threadIdx.x;
        const float4* p = (const float4*)(in + (size_t)t * 8);
        const float4 v0 = p[0];
        const float4 v1 = p[1];
        short8 o;
        o[0] = f2bf(v0.x); o[1] = f2bf(v0.y); o[2] = f2bf(v0.z); o[3] = f2bf(v0.w);
        o[4] = f2bf(v1.x); o[5] = f2bf(v1.y); o[6] = f2bf(v1.z); o[7] = f2bf(v1.w);
        *(short8*)(Ab + (size_t)t * 8) = o;
    }
}

// ---------------------------------------------------------------------------
// GEMM: C[B,M] = A[B,K] * W[M,K]^T — 256x128 tile, BK=32, 4 waves (2x2, wave
// tile 128x64), 16x16x32 MFMA, 3-deep LDS ring (72 KB -> 2 blocks/CU: two
// INDEPENDENT barrier domains per CU), reg-decoupled 2-phase pipeline with
// counted vmcnt(6):
//   ph0: read a1 = cur-tile m4-7 (4 ds) ; issue 6 GLD(t+2) -> buf((t+2)%3) ;
//        MFMA m0-3 (aC,bC from prev iter)
//   ph1: MFMA m4-7 (a1,bC) ; vmcnt(6) ; barrier ;
//        read aC (m0-3) + bC (n0-3) from buf((t+1)%3)   [consumed next iter]
// Hazard audit: identical to r12 (verified, absmax 2.0).
// LDS swizzle FIX (r12 bug): BK=32 rows = 4 x 16B units; the conflict-free
// involution (verified r4/r5, 0 conflicts) is stored unit = u ^ ((row>>1)&3):
// b128 slot = 4*(row&1) + u^((row>>1)&3) covers 8 slots x 2 lanes per 16-row
// group (2-way = free). r12's u^(row&3) gave 4 slots x 4 lanes = 4-way.
// GLOBAL source inverse-swizzled with the SAME involution (both-sides rule);
// staging dest stays linear (= 16B x tid) as global_load_lds requires.
// ---------------------------------------------------------------------------
#define BM 256
#define BN 128
#define BK 32
#define NT (K_DIM / BK)   // 128
#define BUFS 12288        // shorts per ring slot (A 8192 | B 4096) = 24 KB

#define GLD(src, dst) \
    __builtin_amdgcn_global_load_lds( \
        (const __attribute__((address_space(1))) void*)(src), \
        (__attribute__((address_space(3))) void*)(dst), 16, 0, 0)

#define MFMA(a, b, c) __builtin_amdgcn_mfma_f32_16x16x32_bf16(a, b, c, 0, 0, 0)

__global__ __launch_bounds__(256, 2) void gemm_bt_kernel(const short* __restrict__ A,
                                                         const short* __restrict__ Wd,
                                                         float* __restrict__ C) {
    __shared__ short lds[3 * BUFS];   // 72 KB -> 2 blocks/CU

    const int tid  = threadIdx.x;
    const int wave = tid >> 6;
    const int lane = tid & 63;

    // XCD-chunked swizzle: 512 blocks -> 8 XCDs, chunk = 4 by x 16 bx
    const int bid = blockIdx.x;
    const int xcd = bid & 7;
    const int s   = bid >> 3;                 // 0..63
    const int by  = (xcd >> 1) * 4 + (s >> 4);   // 0..15
    const int bx  = (xcd & 1) * 16 + (s & 15);   // 0..31

    const int rowBase = by * BM;
    const int colBase = bx * BN;

    const int wr = wave >> 1;                 // 0..1  (128-row half)
    const int wc = wave & 1;                  // 0..1  (64-col half)

    // ---- staging: thread covers rows (tid>>2)+c*64, stored unit tid&3 ----
    const int rA0 = tid >> 2;                 // 0..63
    const int uu  = (tid & 3) ^ ((rA0 >> 1) & 3);  // inverse-swizzled unit (FIX)
    const int stOff = rA0 * 32 + (tid & 3) * 8;    // shorts; == tid*8 (linear)
    const short* aSrcB = A  + (size_t)(rowBase + rA0) * K_DIM + uu * 8;
    const short* bSrcB = Wd + (size_t)(colBase + rA0) * K_DIM + uu * 8;

    // stage one tile tt into ring slot base (6 GLDs: A c=0..3, B c=0..1)
#define STAGE(tt, base) { \
        const size_t ko = (size_t)(tt) * BK; \
        GLD(aSrcB + ko,                 &lds[(base) + stOff]); \
        GLD(aSrcB + ko + 1 * 64 * K_DIM, &lds[(base) + 2048 + stOff]); \
        GLD(aSrcB + ko + 2 * 64 * K_DIM, &lds[(base) + 4096 + stOff]); \
        GLD(aSrcB + ko + 3 * 64 * K_DIM, &lds[(base) + 6144 + stOff]); \
        GLD(bSrcB + ko,                 &lds[(base) + 8192 + stOff]); \
        GLD(bSrcB + ko + 1 * 64 * K_DIM, &lds[(base) + 8192 + 2048 + stOff]); }

    // ---- fragment read offsets (shorts, within a ring slot) ----
    const int l15 = lane & 15;
    const int l4  = lane >> 4;                // 0..3 (16B unit)
    const int sx  = (l15 >> 1) & 3;           // (row>>1)&3 per-lane const (FIX)
    const int aRd = (wr * 128 + l15) * 32 + (l4 ^ sx) * 8;          // + m*512
    const int bRd = 8192 + (wc * 64 + l15) * 32 + (l4 ^ sx) * 8;    // + n*512

    f32x4 acc[8][4] = {};
    short8 aC[4], bC[4];      // ph0 operands (loop-carried, read at ph1-end)

    // ---- prologue: stage tiles 0,1 ----
    STAGE(0, 0);
    STAGE(1, BUFS);
    asm volatile("s_waitcnt vmcnt(6)" ::: "memory");   // tile 0 landed
    __builtin_amdgcn_s_barrier();
#pragma unroll
    for (int m = 0; m < 4; ++m) aC[m] = *(const short8*)&lds[aRd + m * 512];
#pragma unroll
    for (int n = 0; n < 4; ++n) bC[n] = *(const short8*)&lds[bRd + n * 512];

    int bi = 0;                               // t % 3
    for (int t = 0; t < NT; ++t) {
        const int cur  = bi * BUFS;
        const int bn1i = (bi + 1 < 3) ? (bi + 1) : 0;     // (t+1)%3
        const int bn2i = (bn1i + 1 < 3) ? (bn1i + 1) : 0; // (t+2)%3
        const int bn1  = bn1i * BUFS;
        const int bn2  = bn2i * BUFS;
        const int t2c  = (t + 2 < NT) ? (t + 2) : (NT - 1);

        // ---- ph0: read a1 (m4-7) ; 6 GLD(t+2) ; MFMA m0-3 ----
        short8 a1[4];
#pragma unroll
        for (int m = 0; m < 4; ++m)
            a1[m] = *(const short8*)&lds[cur + aRd + (m + 4) * 512];
        STAGE(t2c, bn2);
        __builtin_amdgcn_s_setprio(1);
#pragma unroll
        for (int m = 0; m < 4; ++m)
#pragma unroll
            for (int n = 0; n < 4; ++n)
                acc[m][n] = MFMA(aC[m], bC[n], acc[m][n]);
        __builtin_amdgcn_s_setprio(0);

        // ---- ph1: MFMA m4-7 ; vmcnt(6)+barrier ; read next-tile frags ----
        __builtin_amdgcn_s_setprio(1);
#pragma unroll
        for (int m = 0; m < 4; ++m)
#pragma unroll
            for (int n = 0; n < 4; ++n)
                acc[m + 4][n] = MFMA(a1[m], bC[n], acc[m + 4][n]);
        __builtin_amdgcn_s_setprio(0);
        asm volatile("s_waitcnt vmcnt(6)" ::: "memory");   // tile t+1 landed
        __builtin_amdgcn_s_barrier();
#pragma unroll
        for (int m = 0; m < 4; ++m)
            aC[m] = *(const short8*)&lds[bn1 + aRd + m * 512];
#pragma unroll
        for (int n = 0; n < 4; ++n)
            bC[n] = *(const short8*)&lds[bn1 + bRd + n * 512];

        bi = bn1i;
    }

    // epilogue: C/D layout col = lane&15, row = (lane>>4)*4 + reg
    const int r0 = rowBase + wr * 128 + l4 * 4;
    const int c0 = colBase + wc * 64 + l15;
#pragma unroll
    for (int m = 0; m < 8; ++m)
#pragma unroll
        for (int n = 0; n < 4; ++n) {
            float* cp = C + (size_t)(r0 + m * 16) * M_DIM + (c0 + n * 16);
#pragma unroll
            for (int reg = 0; reg < 4; ++reg)
                cp[(size_t)reg * M_DIM] = acc[m][n][reg];
        }
}

// ---------------------------------------------------------------------------
extern "C" void kernel_launch(void* const* d_in, const int* in_sizes, int n_in,
                              void* d_out, int out_size, void* d_ws, size_t ws_size,
                              hipStream_t stream) {
    const float* inp  = (const float*)d_in[0];
    const int*   qidx = (const int*)d_in[1];
    const float* cb   = (const float*)d_in[2];
    float* out = (float*)d_out;

    short* Wb = (short*)d_ws;
    short* Ab = Wb + (size_t)M_DIM * K_DIM;

    prep_kernel<<<16384, 256, 0, stream>>>(qidx, cb, Wb, inp, Ab);

    gemm_bt_kernel<<<512, 256, 0, stream>>>(Ab, Wb, out);
}

// Round 14
// 133.386 us; speedup vs baseline: 1.1992x; 1.1979x over previous
//
#include <hip/hip_runtime.h>
#include <hip/hip_bf16.h>

#define B_DIM 4096
#define M_DIM 4096
#define K_DIM 4096
#define NCODE 512

typedef __attribute__((ext_vector_type(4))) float f32x4;
typedef __attribute__((ext_vector_type(8))) short short8;

__device__ __forceinline__ unsigned short f2bf(float f) {
    union { float f; unsigned u; } c; c.f = f;
    unsigned u = c.u;
    return (unsigned short)((u + 0x7FFFu + ((u >> 16) & 1u)) >> 16);
}

// ---------------------------------------------------------------------------
// Fused prep: blocks [0,8192) dequantize codes -> bf16 W; [8192,16384) cvt A.
// Memory-bound at ~6.8 TB/s effective (Q/codebook L2-resident) — at roofline.
// ---------------------------------------------------------------------------
__global__ __launch_bounds__(256) void prep_kernel(const int* __restrict__ Q,
                                                   const float* __restrict__ cb,
                                                   short* __restrict__ Wout,
                                                   const float* __restrict__ in,
                                                   short* __restrict__ Ab) {
    const int b = blockIdx.x;
    if (b < 8192) {
        const int t = b * 256 + threadIdx.x;
        const int code = Q[t] & 0xFFFF;
        const float4* g = (const float4*)(cb + (size_t)code * 8);
        const float4 v0 = g[0];
        const float4 v1 = g[1];
        short8 o;
        o[0] = f2bf(v0.x); o[1] = f2bf(v0.y); o[2] = f2bf(v0.z); o[3] = f2bf(v0.w);
        o[4] = f2bf(v1.x); o[5] = f2bf(v1.y); o[6] = f2bf(v1.z); o[7] = f2bf(v1.w);
        *(short8*)(Wout + (size_t)t * 8) = o;
    } else {
        const int t = (b - 8192) * 256 + threadIdx.x;
        const float4* p = (const float4*)(in + (size_t)t * 8);
        const float4 v0 = p[0];
        const float4 v1 = p[1];
        short8 o;
        o[0] = f2bf(v0.x); o[1] = f2bf(v0.y); o[2] = f2bf(v0.z); o[3] = f2bf(v0.w);
        o[4] = f2bf(v1.x); o[5] = f2bf(v1.y); o[6] = f2bf(v1.z); o[7] = f2bf(v1.w);
        *(short8*)(Ab + (size_t)t * 8) = o;
    }
}

// ---------------------------------------------------------------------------
// GEMM: C[B,M] = A[B,K] * W[M,K]^T — 256x256 tile, BK=64, 8 waves (2x4, wave
// tile 128x64), 16x16x32 MFMA, 2-deep LDS ring (128 KB), 4-phase register
// pipeline (phase p reads phase p+1's frags), 2 barriers/iter.
//   ph0: MFMA m0-3/h0 (frags from prev ph3/prologue) || read aH0[4-7] || 4 A-GLD(t+1)
//   ph1: MFMA m4-7/h0 || read aH1[0-3], bH1[0-3] || 4 B-GLD(t+1)
//   ph2: MFMA m0-3/h1 || read aH1[4-7] ; vmcnt(0) ; barrier  (t+1 published)
//   ph3: MFMA m4-7/h1 || read next-tile ph0 frags from bufn ;
//        lgkmcnt(8) ; barrier  (all buf(t) reads drained)
// Hazard proof:
//  - visibility: each wave's 8 GLDs for t+1 issue in ph0/ph1; its vmcnt(0) at
//    ph2-end drains them; barrier joins all waves. ph3's bufn reads follow.
//  - overwrite: GLD(t+2)->buf(t&1) issues at iter t+1 ph0, after iter t's
//    final barrier; all buf(t) reads were consumed by iter-t MFMAs (compiler
//    waits) and fenced by lgkmcnt(8) (ph3's 8 bufn reads are the newest 8).
//  - prologue: stage tile 0, vmcnt(0)+barrier, read ph0 frags.
// LDS swizzle (BK=64 rows = 8 x 16B units): stored unit = u ^ (row&7);
// read-side XOR folds to per-lane constant; GLOBAL source inverse-swizzled
// (both-sides rule). Measured: SQ_LDS_BANK_CONFLICT = 0.
// Cycle model @ iter=4270 cy: MFMA 2483 cy/SIMD (58%), LDS ~2816 cy/CU (66%)
// — jointly limited; six alternative schedule families all measured worse.
// ---------------------------------------------------------------------------
#define BM 256
#define BN 256
#define BK 64
#define NT (K_DIM / BK)   // 64

#define GLD(src, dst) \
    __builtin_amdgcn_global_load_lds( \
        (const __attribute__((address_space(1))) void*)(src), \
        (__attribute__((address_space(3))) void*)(dst), 16, 0, 0)

#define MFMA(a, b, c) __builtin_amdgcn_mfma_f32_16x16x32_bf16(a, b, c, 0, 0, 0)

__global__ __launch_bounds__(512, 2) void gemm_bt_kernel(const short* __restrict__ A,
                                                         const short* __restrict__ Wd,
                                                         float* __restrict__ C) {
    __shared__ short lds[2 * 32768];   // 2 bufs x (A 32KB | B 32KB) = 128 KB

    const int tid  = threadIdx.x;
    const int wave = tid >> 6;
    const int lane = tid & 63;

    // XCD-chunked swizzle: 256 blocks -> 8 XCDs, each a 4x8 block chunk
    const int bid = blockIdx.x;
    const int xcd = bid & 7;
    const int s   = bid >> 3;
    const int by  = (xcd >> 1) * 4 + (s >> 3);
    const int bx  = (xcd & 1) * 8 + (s & 7);

    const int rowBase = by * BM;
    const int colBase = bx * BN;

    const int wr = wave >> 2;                 // 0..1  (128-row half)
    const int wc = wave & 3;                  // 0..3  (64-col quarter)

    // ---- staging: thread covers rows (tid>>3)+c*64, stored unit tid&7 ----
    const int rA0 = tid >> 3;                 // 0..63
    const int uu  = (tid & 7) ^ (rA0 & 7);    // inverse-swizzled logical unit
    const int stOff = rA0 * 64 + (tid & 7) * 8;   // shorts; +c*4096
    const short* aSrcB = A  + (size_t)(rowBase + rA0) * K_DIM + uu * 8;
    const short* bSrcB = Wd + (size_t)(colBase + rA0) * K_DIM + uu * 8;

    // ---- fragment read offsets (shorts) ----
    const int l15 = lane & 15;
    const int l4  = lane >> 4;
    const int uk0 = ((l4 ^ (l15 & 7))) * 8;   // h=0 stored-unit offset
    const int uk1 = uk0 ^ 32;                 // h=1 (unit XOR 4)
    const int aRow = (wr * 128 + l15) * 64;           // + m*1024 + ukh
    const int bRow = 16384 + (wc * 64 + l15) * 64;    // + n*1024 + ukh

    f32x4 acc[8][4] = {};
    short8 aC[4], bC[4];      // ph0 operands (loop-carried, written at ph3)

    // ---- prologue: stage tile 0 into buf0, publish, read ph0 frags ----
#pragma unroll
    for (int c = 0; c < 4; ++c)
        GLD(aSrcB + c * (64 * K_DIM), &lds[c * 4096 + stOff]);
#pragma unroll
    for (int c = 0; c < 4; ++c)
        GLD(bSrcB + c * (64 * K_DIM), &lds[16384 + c * 4096 + stOff]);
    asm volatile("s_waitcnt vmcnt(0)" ::: "memory");
    __builtin_amdgcn_s_barrier();
#pragma unroll
    for (int m = 0; m < 4; ++m) aC[m] = *(const short8*)&lds[aRow + m * 1024 + uk0];
#pragma unroll
    for (int n = 0; n < 4; ++n) bC[n] = *(const short8*)&lds[bRow + n * 1024 + uk0];

    for (int t = 0; t < NT; ++t) {
        const int buf  = (t & 1) * 32768;
        const int bufn = buf ^ 32768;
        const size_t kpre = (size_t)(((t + 1 < NT) ? (t + 1) : (NT - 1)) * BK);

        // ---- ph0: MFMA m0-3 x h0 ; read aH0[4-7] ; issue 4 A-GLD(t+1) ----
        short8 a1h0[4];
#pragma unroll
        for (int m = 0; m < 4; ++m)
            a1h0[m] = *(const short8*)&lds[buf + aRow + (m + 4) * 1024 + uk0];
#pragma unroll
        for (int c = 0; c < 4; ++c)
            GLD(aSrcB + kpre + c * (64 * K_DIM), &lds[bufn + c * 4096 + stOff]);
        __builtin_amdgcn_s_setprio(1);
#pragma unroll
        for (int m = 0; m < 4; ++m)
#pragma unroll
            for (int n = 0; n < 4; ++n)
                acc[m][n] = MFMA(aC[m], bC[n], acc[m][n]);
        __builtin_amdgcn_s_setprio(0);

        // ---- ph1: MFMA m4-7 x h0 ; read aH1[0-3], bH1[0-3] ; 4 B-GLD ----
        short8 a0h1[4], b1[4];
#pragma unroll
        for (int m = 0; m < 4; ++m)
            a0h1[m] = *(const short8*)&lds[buf + aRow + m * 1024 + uk1];
#pragma unroll
        for (int n = 0; n < 4; ++n)
            b1[n] = *(const short8*)&lds[buf + bRow + n * 1024 + uk1];
#pragma unroll
        for (int c = 0; c < 4; ++c)
            GLD(bSrcB + kpre + c * (64 * K_DIM), &lds[bufn + 16384 + c * 4096 + stOff]);
        __builtin_amdgcn_s_setprio(1);
#pragma unroll
        for (int m = 0; m < 4; ++m)
#pragma unroll
            for (int n = 0; n < 4; ++n)
                acc[m + 4][n] = MFMA(a1h0[m], bC[n], acc[m + 4][n]);
        __builtin_amdgcn_s_setprio(0);

        // ---- ph2: MFMA m0-3 x h1 ; read aH1[4-7] ; vmcnt(0)+barrier ----
        short8 a1h1[4];
#pragma unroll
        for (int m = 0; m < 4; ++m)
            a1h1[m] = *(const short8*)&lds[buf + aRow + (m + 4) * 1024 + uk1];
        __builtin_amdgcn_s_setprio(1);
#pragma unroll
        for (int m = 0; m < 4; ++m)
#pragma unroll
            for (int n = 0; n < 4; ++n)
                acc[m][n] = MFMA(a0h1[m], b1[n], acc[m][n]);
        __builtin_amdgcn_s_setprio(0);
        asm volatile("s_waitcnt vmcnt(0)" ::: "memory");   // tile t+1 landed
        __builtin_amdgcn_s_barrier();

        // ---- ph3: MFMA m4-7 x h1 ; read next-tile ph0 frags from bufn ----
#pragma unroll
        for (int m = 0; m < 4; ++m)
            aC[m] = *(const short8*)&lds[bufn + aRow + m * 1024 + uk0];
#pragma unroll
        for (int n = 0; n < 4; ++n)
            bC[n] = *(const short8*)&lds[bufn + bRow + n * 1024 + uk0];
        __builtin_amdgcn_s_setprio(1);
#pragma unroll
        for (int m = 0; m < 4; ++m)
#pragma unroll
            for (int n = 0; n < 4; ++n)
                acc[m + 4][n] = MFMA(a1h1[m], b1[n], acc[m + 4][n]);
        __builtin_amdgcn_s_setprio(0);
        asm volatile("s_waitcnt lgkmcnt(8)" ::: "memory"); // buf(t) reads drained
        __builtin_amdgcn_s_barrier();
    }

    // epilogue: C/D layout col = lane&15, row = (lane>>4)*4 + reg
    const int r0 = rowBase + wr * 128 + l4 * 4;
    const int c0 = colBase + wc * 64 + l15;
#pragma unroll
    for (int m = 0; m < 8; ++m)
#pragma unroll
        for (int n = 0; n < 4; ++n) {
            float* cp = C + (size_t)(r0 + m * 16) * M_DIM + (c0 + n * 16);
#pragma unroll
            for (int reg = 0; reg < 4; ++reg)
                cp[(size_t)reg * M_DIM] = acc[m][n][reg];
        }
}

// ---------------------------------------------------------------------------
extern "C" void kernel_launch(void* const* d_in, const int* in_sizes, int n_in,
                              void* d_out, int out_size, void* d_ws, size_t ws_size,
                              hipStream_t stream) {
    const float* inp  = (const float*)d_in[0];
    const int*   qidx = (const int*)d_in[1];
    const float* cb   = (const float*)d_in[2];
    float* out = (float*)d_out;

    short* Wb = (short*)d_ws;
    short* Ab = Wb + (size_t)M_DIM * K_DIM;

    prep_kernel<<<16384, 256, 0, stream>>>(qidx, cb, Wb, inp, Ab);

    gemm_bt_kernel<<<256, 512, 0, stream>>>(Ab, Wb, out);
}